// Round 7
// baseline (219.099 us; speedup 1.0000x reference)
//
#include <hip/hip_runtime.h>
#include <hip/hip_fp16.h>
#include <cmath>

#define B_SZ 2048
#define D_IN 512
#define U_N  512
#define FD   1024   // D_IN + U_N
#define NRU  4096   // U_N * M_B
#define NRU2 8192   // combined r+u output cols

typedef _Float16 f16x8 __attribute__((ext_vector_type(8)));
typedef float    f32x4 __attribute__((ext_vector_type(4)));

#define TAB_INIT {0.0f, 1.15129254649702f, 2.30258509299405f, \
                  3.45387763949107f, 4.60517018598809f, 5.75646273248511f, \
                  6.90775527898214f, 8.05904782547916f}

// ---------------------------------------------------------------------------
// P1: h = sum_m state[b,u,m]; fused = [f16(inputs), f16(h)]; reset[:,0:512]=f16(inputs)
// ---------------------------------------------------------------------------
__global__ __launch_bounds__(256) void prep_kernel(
    const float* __restrict__ inputs, const float* __restrict__ state,
    __half* __restrict__ fused, __half* __restrict__ reset)
{
    const int b = blockIdx.x;
    const int t = threadIdx.x;

    const float2 iv = *(const float2*)(inputs + (size_t)b * D_IN + t * 2);
    __half2 hv;
    hv.x = __float2half(iv.x);
    hv.y = __float2half(iv.y);
    *(__half2*)(fused + (size_t)b * FD + t * 2) = hv;
    *(__half2*)(reset + (size_t)b * FD + t * 2) = hv;

    const float4* sp = (const float4*)(state + (size_t)b * NRU + t * 16);
    float4 x0 = sp[0], x1 = sp[1], x2 = sp[2], x3 = sp[3];
    float s0 = (x0.x + x0.y) + (x0.z + x0.w) + (x1.x + x1.y) + (x1.z + x1.w);
    float s1 = (x2.x + x2.y) + (x2.z + x2.w) + (x3.x + x3.y) + (x3.z + x3.w);
    __half2 h2;
    h2.x = __float2half(s0);
    h2.y = __float2half(s1);
    *(__half2*)(fused + (size_t)b * FD + D_IN + t * 2) = h2;
}

// ---------------------------------------------------------------------------
// P2 (merged): transpose-convert W_r, W_u, W_d in one launch.
// ---------------------------------------------------------------------------
__global__ __launch_bounds__(256) void convT3_kernel(
    const float* __restrict__ W_r, const float* __restrict__ W_u,
    const float* __restrict__ W_d, __half* __restrict__ WruT,
    __half* __restrict__ WdT)
{
    __shared__ float tile[32][33];
    const int bx = blockIdx.x;
    const float* W;
    __half* Wt;
    int N, nt;
    if (bx < 128)      { W = W_r; Wt = WruT;                    N = NRU; nt = bx * 32; }
    else if (bx < 256) { W = W_u; Wt = WruT + (size_t)NRU * FD; N = NRU; nt = (bx - 128) * 32; }
    else               { W = W_d; Wt = WdT;                     N = U_N; nt = (bx - 256) * 32; }

    const int kt = blockIdx.y * 32;
    const int t  = threadIdx.x;
    const int c  = t & 31;
    const int r4 = t >> 5;

#pragma unroll
    for (int i = 0; i < 4; i++) {
        int r = r4 + i * 8;
        tile[r][c] = W[(size_t)(kt + r) * N + nt + c];
    }
    __syncthreads();
#pragma unroll
    for (int i = 0; i < 4; i++) {
        int rr = r4 + i * 8;
        Wt[(size_t)(nt + rr) * FD + kt + c] = __float2half(tile[c][rr]);
    }
}

// ---------------------------------------------------------------------------
// GEMM: [M,K](f16) @ [N,K](f16)^T, BMx128 tile, BK=32.
// VGPR-mediated double-buffered pipeline: global->VGPR loads for tile k+1
// issued before compute of tile k; vmcnt wait hides under MFMA; ds_write to
// the alternate buffer; barrier drains only LDS (vmcnt already 0 -> no
// m97-style global drain stall).
// LDS rows are 64B (4 granules); granule g of row r lives at slot
// g ^ ((r>>1)&3): quad-reads spread 2 words/bank (free), writes minimal.
// EPI=0 (BM=64): qk = tanhf(acc + biasA)   (detect path)
// EPI=1 (BM=128): fused CTGRU gate epilogue (r: q->reset, u: ski->skibuf)
// ---------------------------------------------------------------------------
template <int BM, int EPI>
__global__ __launch_bounds__(256) void gemm_k(
    const __half* __restrict__ A, const __half* __restrict__ Bt,
    const float* __restrict__ biasA, const float* __restrict__ biasB, int nsplit,
    float* __restrict__ C, int Ncols,
    const float* __restrict__ state, __half* __restrict__ resetw,
    __half* __restrict__ skibuf, int K)
{
    extern __shared__ __align__(16) char smem[];
    constexpr int TILEH = (BM + 128) * 32;   // halves per buffer
    __half* s0 = (__half*)smem;
    __half* s1 = s0 + TILEH;

    const int t    = threadIdx.x;
    const int m0   = blockIdx.y * BM;
    const int n0   = blockIdx.x << 7;
    const int lane = t & 63;
    const int w    = t >> 6;
    const int m16  = lane & 15;
    const int quad = lane >> 4;
    constexpr int MI = BM / 32;        // m-frags per wave
    constexpr int GA = BM / 64;        // A granules per thread
    const int wm = (w & 1) * (BM / 2);
    const int wn = (w >> 1) << 6;
    const int strip = w >> 1;

    f32x4 acc[MI][4];
#pragma unroll
    for (int i = 0; i < MI; i++)
#pragma unroll
        for (int j = 0; j < 4; j++)
#pragma unroll
            for (int r = 0; r < 4; r++) acc[i][j][r] = 0.f;

    // staging assignment: thread t owns GA granules of A, 2 of B (16B each)
    const __half* gA[GA];
    int lA[GA];
#pragma unroll
    for (int i = 0; i < GA; i++) {
        const int off = t * 16 + i * 4096;         // byte offset in A tile
        const int row = off >> 6;
        const int g   = (off >> 4) & 3;
        gA[i] = A + (size_t)(m0 + row) * K + g * 8;
        lA[i] = row * 32 + ((g ^ ((row >> 1) & 3)) << 3);
    }
    const __half* gB[2];
    int lB[2];
#pragma unroll
    for (int i = 0; i < 2; i++) {
        const int off = t * 16 + i * 4096;         // byte offset in B tile
        const int row = off >> 6;
        const int g   = (off >> 4) & 3;
        gB[i] = Bt + (size_t)(n0 + row) * K + g * 8;
        lB[i] = BM * 32 + row * 32 + ((g ^ ((row >> 1) & 3)) << 3);
    }

    // prologue: stage tile 0 into s0
    {
        uint4 ra[GA], rb[2];
#pragma unroll
        for (int i = 0; i < GA; i++) ra[i] = *(const uint4*)(gA[i]);
#pragma unroll
        for (int i = 0; i < 2; i++)  rb[i] = *(const uint4*)(gB[i]);
#pragma unroll
        for (int i = 0; i < GA; i++) *(uint4*)(s0 + lA[i]) = ra[i];
#pragma unroll
        for (int i = 0; i < 2; i++)  *(uint4*)(s0 + lB[i]) = rb[i];
    }
    __syncthreads();

    auto step = [&](const __half* curb, __half* nxtb, int konext) {
        uint4 ra[GA], rb[2];
#pragma unroll
        for (int i = 0; i < GA; i++) ra[i] = *(const uint4*)(gA[i] + konext);
#pragma unroll
        for (int i = 0; i < 2; i++)  rb[i] = *(const uint4*)(gB[i] + konext);

        f16x8 af[MI], bf[4];
#pragma unroll
        for (int mi = 0; mi < MI; mi++) {
            const int row = wm + mi * 16 + m16;
            af[mi] = *(const f16x8*)(curb + row * 32 + ((quad ^ ((row >> 1) & 3)) << 3));
        }
#pragma unroll
        for (int ni = 0; ni < 4; ni++) {
            const int row = wn + ni * 16 + m16;
            bf[ni] = *(const f16x8*)(curb + BM * 32 + row * 32 + ((quad ^ ((row >> 1) & 3)) << 3));
        }
#pragma unroll
        for (int mi = 0; mi < MI; mi++)
#pragma unroll
            for (int ni = 0; ni < 4; ni++)
                acc[mi][ni] = __builtin_amdgcn_mfma_f32_16x16x32_f16(
                    af[mi], bf[ni], acc[mi][ni], 0, 0, 0);

#pragma unroll
        for (int i = 0; i < GA; i++) *(uint4*)(nxtb + lA[i]) = ra[i];
#pragma unroll
        for (int i = 0; i < 2; i++)  *(uint4*)(nxtb + lB[i]) = rb[i];
        __syncthreads();
    };

    const int NI = K >> 5;                 // 32 for K=1024 (even)
    for (int k = 0; k < NI; k += 2) {
        const int k1 = k + 1;                          // < NI (NI even)
        const int k2 = (k + 2 < NI) ? k + 2 : NI - 1;  // clamp: redundant reload
        step(s0, s1, k1 << 5);
        step(s1, s0, k2 << 5);
    }

    if constexpr (EPI == 0) {
        // -------- detect: tanh + plain store (BM == 64) --------
#pragma unroll
        for (int mi = 0; mi < MI; mi++) {
#pragma unroll
            for (int ni = 0; ni < 4; ni++) {
                const int col = n0 + wn + ni * 16 + m16;
                const float bv = biasA[col];
#pragma unroll
                for (int r = 0; r < 4; r++) {
                    const int row = m0 + wm + mi * 16 + quad * 4 + r;
                    C[(size_t)row * Ncols + col] = tanhf(acc[mi][ni][r] + bv);
                }
            }
        }
    } else {
        // -------- fused gate epilogue, coalesced (BM == 128) --------
        __syncthreads();
        float*  ebuf = (float*)smem;                    // [128][36]
        __half* qbuf = (__half*)(smem + 128 * 36 * 4);  // [128][16]
        const bool is_r = (n0 < nsplit);
        const float* bp = is_r ? biasA : biasB;
        const int n0r = is_r ? n0 : n0 - nsplit;   // col base in r/u space
        const float TAB[8] = TAB_INIT;
        const int ug  = t & 3;
        const int s   = ug >> 1;
        const int g   = ug & 1;
        const int bl0 = t >> 2;        // 0..63

        for (int ni = 0; ni < 4; ni++) {
            const float bv = bp[n0r + strip * 64 + ni * 16 + m16];
#pragma unroll
            for (int mi = 0; mi < 4; mi++)
#pragma unroll
                for (int r = 0; r < 4; r++)
                    ebuf[(wm + mi * 16 + quad * 4 + r) * 36 + strip * 16 + m16] =
                        acc[mi][ni][r] + bv;
            __syncthreads();

#pragma unroll
            for (int p = 0; p < 2; p++) {
                const int b_loc = bl0 + p * 64;
                const int b = m0 + b_loc;
                const float* rowp = ebuf + b_loc * 36 + ug * 8;
                float v[8];
                *(float4*)&v[0] = *(const float4*)rowp;
                *(float4*)&v[4] = *(const float4*)(rowp + 4);

                float e[8];
                float sum = 0.f;
#pragma unroll
                for (int i = 0; i < 8; i++) {
                    float d = v[i] - TAB[i];
                    e[i] = __expf(-d * d);
                    sum += e[i];
                }
                const int col = n0r + s * 64 + ni * 16 + g * 8;  // flat (u*8) col
                if (is_r) {
                    const float4 h0 = *(const float4*)(state + (size_t)b * NRU + col);
                    const float4 h1 = *(const float4*)(state + (size_t)b * NRU + col + 4);
                    const float hv[8] = {h0.x, h0.y, h0.z, h0.w, h1.x, h1.y, h1.z, h1.w};
                    float qn = 0.f;
#pragma unroll
                    for (int i = 0; i < 8; i++) qn += e[i] * hv[i];
                    qbuf[b_loc * 16 + (s * 8 + ni * 2 + g)] = __float2half(qn / sum);
                } else {
                    const float inv = 1.0f / sum;
                    __half2 o[4];
#pragma unroll
                    for (int i = 0; i < 4; i++) {
                        o[i].x = __float2half(e[2 * i] * inv);
                        o[i].y = __float2half(e[2 * i + 1] * inv);
                    }
                    *(uint4*)(skibuf + (size_t)b * NRU + col) = *(uint4*)o;
                }
            }
            __syncthreads();
        }
        if (is_r) {
            const int b_loc = t >> 1;
            const int j = t & 1;
            uint4 qv = *(uint4*)(qbuf + b_loc * 16 + j * 8);
            *(uint4*)(resetw + (size_t)(m0 + b_loc) * FD + D_IN + (n0r >> 3) + j * 8) = qv;
        }
    }
}

// ---------------------------------------------------------------------------
// E2: h_hat_next = ((1-ski)*h_hat + ski*qk) * exp(-el/tau); h_next = sum_m
// ---------------------------------------------------------------------------
__global__ __launch_bounds__(256) void final_kernel(
    const __half* __restrict__ skibuf, const float* __restrict__ state,
    const float* __restrict__ qk, const float* __restrict__ elapsed,
    float* __restrict__ out0, float* __restrict__ out1)
{
    const int idx = blockIdx.x * 256 + threadIdx.x;
    const int b = idx >> 9;
    const int u = idx & 511;

    const float INV_TAU[8] = {1.0f, 0.316227766016838f, 0.1f, 0.0316227766016838f,
                              0.01f, 0.00316227766016838f, 0.001f, 0.000316227766016838f};

    const uint4 sr = *(const uint4*)(skibuf + (size_t)b * NRU + u * 8);
    const __half2* sh = (const __half2*)&sr;
    float sk[8];
#pragma unroll
    for (int i = 0; i < 4; i++) {
        float2 f2 = __half22float2(sh[i]);
        sk[2 * i]     = f2.x;
        sk[2 * i + 1] = f2.y;
    }

    const float4* hh = (const float4*)(state + ((size_t)b * NRU + u * 8));
    float4 h0 = hh[0], h1 = hh[1];
    float h[8] = {h0.x, h0.y, h0.z, h0.w, h1.x, h1.y, h1.z, h1.w};

    const float q  = qk[(size_t)b * U_N + u];
    const float el = elapsed[b];

    float hn[8];
    float acc = 0.f;
#pragma unroll
    for (int i = 0; i < 8; i++) {
        const float et = __expf(-el * INV_TAU[i]);
        hn[i] = ((1.0f - sk[i]) * h[i] + sk[i] * q) * et;
        acc += hn[i];
    }

    float4* o = (float4*)(out1 + ((size_t)b * NRU + u * 8));
    o[0] = make_float4(hn[0], hn[1], hn[2], hn[3]);
    o[1] = make_float4(hn[4], hn[5], hn[6], hn[7]);
    out0[(size_t)b * U_N + u] = acc;
}

// ---------------------------------------------------------------------------
extern "C" void kernel_launch(void* const* d_in, const int* in_sizes, int n_in,
                              void* d_out, int out_size, void* d_ws, size_t ws_size,
                              hipStream_t stream)
{
    (void)in_sizes; (void)n_in; (void)out_size; (void)ws_size;

    const float* inputs  = (const float*)d_in[0];
    const float* elapsed = (const float*)d_in[1];
    const float* state   = (const float*)d_in[2];
    const float* W_r     = (const float*)d_in[3];
    const float* b_r     = (const float*)d_in[4];
    const float* W_d     = (const float*)d_in[5];
    const float* b_d     = (const float*)d_in[6];
    const float* W_u     = (const float*)d_in[7];
    const float* b_u     = (const float*)d_in[8];
    float* out = (float*)d_out;

    char* ws = (char*)d_ws;
    __half* fused  = (__half*)(ws);                         //  4 MB [2048,1024]
    __half* reset  = (__half*)(ws + ((size_t)4  << 20));    //  4 MB [2048,1024]
    __half* WruT   = (__half*)(ws + ((size_t)8  << 20));    // 16 MB [8192,1024]
    __half* WdT    = (__half*)(ws + ((size_t)24 << 20));    //  1 MB [512,1024]
    __half* skibuf = (__half*)(ws + ((size_t)25 << 20));    // 16 MB [2048,4096]
    float*  qk     = (float*) (ws + ((size_t)41 << 20));    //  4 MB [2048,512]

    prep_kernel<<<B_SZ, 256, 0, stream>>>(inputs, state, fused, reset);
    convT3_kernel<<<dim3(272, FD / 32), 256, 0, stream>>>(W_r, W_u, W_d, WruT, WdT);

    // combined r+u GEMM with fused gate epilogue: [2048,1024] x [8192,1024]^T
    gemm_k<128, 1><<<dim3(NRU2 / 128, B_SZ / 128), 256, 32768, stream>>>(
        fused, WruT, b_r, b_u, NRU, nullptr, 0, state, reset, skibuf, FD);

    // detect GEMM: [2048,1024] x [512,1024]^T -> qk fp32 (tanh)
    gemm_k<64, 0><<<dim3(U_N / 128, B_SZ / 64), 256, 24576, stream>>>(
        reset, WdT, b_d, nullptr, 1 << 30, qk, U_N, nullptr, nullptr, nullptr, FD);

    final_kernel<<<(B_SZ * U_N) / 256, 256, 0, stream>>>(skibuf, state, qk, elapsed, out,
                                                         out + (size_t)B_SZ * U_N);
}